// Round 20
// baseline (160.981 us; speedup 1.0000x reference)
//
#include <hip/hip_runtime.h>
#include <hip/hip_bf16.h>

// ---------------------------------------------------------------------------
// Problem constants: B=4, T=2048, C=1024, H=16, hd=64
// ---------------------------------------------------------------------------
#define BATCH 4
#define TSEQ  2048
#define CDIM  1024
#define NHEAD 16
#define HDIM  64
#define C3    3072
#define MROWS (BATCH * TSEQ)   // 8192

// scale * log2(e): folded into w_attn q-columns + b_attn q-part so QK^T
// emits exp2-domain scores directly.
#define QSCALE 0.18033688011112f

typedef short bf16x8 __attribute__((ext_vector_type(8)));
typedef short short8 __attribute__((ext_vector_type(8)));
typedef __bf16 bf16v8 __attribute__((ext_vector_type(8)));
typedef float f32x4 __attribute__((ext_vector_type(4)));

#define AS1 __attribute__((address_space(1)))
#define AS3 __attribute__((address_space(3)))

// raw v_exp_f32 (1 TRANS op) vs libm exp2f (denormal-guard ~5 ops). Inputs
// are bounded exp2-domain scores -> raw is exact for our range. (r15: -23%)
#if __has_builtin(__builtin_amdgcn_exp2f)
#define EXP2F(x) __builtin_amdgcn_exp2f(x)
#else
#define EXP2F(x) exp2f(x)
#endif

__device__ __forceinline__ short f2bf(float x) {
    unsigned int u = __builtin_bit_cast(unsigned int, x);
    u += 0x7fffu + ((u >> 16) & 1u);   // round-to-nearest-even
    return (short)(u >> 16);
}

__device__ __forceinline__ unsigned int cvtpk(float lo, float hi) {
    unsigned int r;
    asm("v_cvt_pk_bf16_f32 %0, %1, %2" : "=v"(r) : "v"(lo), "v"(hi));
    return r;
}

__device__ __forceinline__ f32x4 mfma16(bf16x8 a, bf16x8 b, f32x4 c) {
    return __builtin_amdgcn_mfma_f32_16x16x32_bf16(
        __builtin_bit_cast(bf16v8, a), __builtin_bit_cast(bf16v8, b), c, 0, 0, 0);
}

// ---------------------------------------------------------------------------
// Merged prep: z=0 -> x fp32->bf16 convert; z=1 -> w_attn transpose (q-cols
// prescaled); z=2 -> w_proj transpose.
// ---------------------------------------------------------------------------
__global__ void prep_kernel(const float* __restrict__ x, short* __restrict__ x_bf,
                            const float* __restrict__ wA, short* __restrict__ wAT,
                            const float* __restrict__ wP, short* __restrict__ wPT,
                            float qs) {
    const int tx = threadIdx.x, ty = threadIdx.y;   // (32,8)
    if (blockIdx.z == 0) {
        const int i = (blockIdx.y * 128 + blockIdx.x) * 256 + ty * 32 + tx;
        float4 a = ((const float4*)x)[2 * i];
        float4 b = ((const float4*)x)[2 * i + 1];
        short8 o;
        o[0] = f2bf(a.x); o[1] = f2bf(a.y); o[2] = f2bf(a.z); o[3] = f2bf(a.w);
        o[4] = f2bf(b.x); o[5] = f2bf(b.y); o[6] = f2bf(b.z); o[7] = f2bf(b.w);
        ((short8*)x_bf)[i] = o;
        return;
    }
    const float* in;
    short* out;
    int N, qcols;
    float sc;
    if (blockIdx.z == 1) {
        if (blockIdx.x >= C3 / 32) return;
        in = wA; out = wAT; N = C3; qcols = CDIM; sc = qs;
    } else {
        if (blockIdx.x >= CDIM / 32) return;
        in = wP; out = wPT; N = CDIM; qcols = 0; sc = 1.0f;
    }
    __shared__ float tile[32][33];
    const int n0 = blockIdx.x * 32, k0 = blockIdx.y * 32;
#pragma unroll
    for (int j = 0; j < 4; ++j)
        tile[ty + j * 8][tx] = in[(size_t)(k0 + ty + j * 8) * N + n0 + tx];
    __syncthreads();
#pragma unroll
    for (int j = 0; j < 4; ++j) {
        const int n = n0 + ty + j * 8;
        const float s = (n < qcols) ? sc : 1.0f;
        out[(size_t)n * CDIM + k0 + tx] = f2bf(tile[tx][ty + j * 8] * s);
    }
}

// ---------------------------------------------------------------------------
// bf16 GEMM v3.1 (round-13/15 proven): BK=32 3-buffer rotation, counted-vmcnt
// pipeline, issue-early staging, chunk-XOR swizzle, bijective XCD swizzle.
// GEMM1 uses <2,4,256> (64x64 per-wave tile — verified sweet spot of this
// structure family: r16's 128x64 and r18's 32x64 both regressed to ~70-73us).
// ---------------------------------------------------------------------------
template <typename OutT, int WAVES_M, int WAVES_N, int BN>
__global__ __launch_bounds__(512, 4) void gemm3_kernel(
    const short* __restrict__ A, const short* __restrict__ Bt,
    const float* __restrict__ bias, OutT* __restrict__ out,
    int M, int N, int K, int qcols, float qs) {
    constexpr int BM = 128;
    constexpr int MF = BM / (WAVES_M * 16);
    constexpr int NF = BN / (WAVES_N * 16);
    constexpr int BLOADS = BN / 128;
    __shared__ alignas(16) short Ab[3][BM * 32];
    __shared__ alignas(16) short Bb[3][BN * 32];

    const int tid = threadIdx.x;
    const int lane = tid & 63;
    const int w = tid >> 6;
    const int wm = w / WAVES_N;
    const int wn = w % WAVES_N;

    const int nwg = gridDim.x * gridDim.y;
    const int lid = blockIdx.y * gridDim.x + blockIdx.x;
    const int swz = (lid & 7) * (nwg >> 3) + (lid >> 3);
    const int m0 = (swz / gridDim.x) * BM;
    const int n0 = (swz % gridDim.x) * BN;

    const int NT = K >> 5;

    const int fr = lane & 15;
    const int ch = lane >> 4;

    f32x4 acc[MF][NF] = {};

    const int rA  = tid >> 2;
    const int lcA = (tid & 3) ^ ((rA >> 1) & 3);
    const short* gA = A + (size_t)(m0 + rA) * K + lcA * 8;
    const short* gB[BLOADS];
#pragma unroll
    for (int i = 0; i < BLOADS; ++i) {
        const int s = tid + i * 512;
        const int r = s >> 2;
        const int lc = (s & 3) ^ ((r >> 1) & 3);
        gB[i] = Bt + (size_t)(n0 + r) * K + lc * 8;
    }

    int aoff[MF], boff[NF];
#pragma unroll
    for (int f = 0; f < MF; ++f) {
        const int r = wm * (BM / WAVES_M) + f * 16 + fr;
        aoff[f] = r * 32 + (ch ^ ((r >> 1) & 3)) * 8;
    }
#pragma unroll
    for (int f = 0; f < NF; ++f) {
        const int r = wn * (BN / WAVES_N) + f * 16 + fr;
        boff[f] = r * 32 + (ch ^ ((r >> 1) & 3)) * 8;
    }

#define GSTAGE(buf, kt)                                                          \
    do {                                                                         \
        __builtin_amdgcn_global_load_lds((const AS1 void*)(gA + (kt)),           \
            (AS3 void*)&Ab[buf][w * 512], 16, 0, 0);                             \
        _Pragma("unroll")                                                        \
        for (int i = 0; i < BLOADS; ++i)                                         \
            __builtin_amdgcn_global_load_lds((const AS1 void*)(gB[i] + (kt)),    \
                (AS3 void*)&Bb[buf][i * 4096 + w * 512], 16, 0, 0);              \
    } while (0)

#define GITER(BUF, T)                                                            \
    do {                                                                         \
        if constexpr (BLOADS == 2) {                                             \
            asm volatile("s_waitcnt vmcnt(3)" ::: "memory");                     \
        } else {                                                                 \
            asm volatile("s_waitcnt vmcnt(2)" ::: "memory");                     \
        }                                                                        \
        __builtin_amdgcn_s_barrier();                                            \
        const int ktn = (((T) + 2 < NT) ? ((T) + 2) : 0) * 32;                   \
        GSTAGE((BUF + 2) % 3, ktn);                                              \
        __builtin_amdgcn_sched_barrier(0);                                       \
        bf16x8 af[MF], bfv[NF];                                                  \
        _Pragma("unroll")                                                        \
        for (int f = 0; f < MF; ++f)                                             \
            af[f] = *(const bf16x8*)&Ab[BUF][aoff[f]];                           \
        _Pragma("unroll")                                                        \
        for (int f = 0; f < NF; ++f)                                             \
            bfv[f] = *(const bf16x8*)&Bb[BUF][boff[f]];                          \
        _Pragma("unroll")                                                        \
        for (int mf = 0; mf < MF; ++mf)                                          \
            _Pragma("unroll")                                                    \
            for (int nf = 0; nf < NF; ++nf)                                      \
                acc[mf][nf] = mfma16(af[mf], bfv[nf], acc[mf][nf]);              \
    } while (0)

    GSTAGE(0, 0);
    GSTAGE(1, 32);

    int t = 0;
    for (; t + 3 <= NT; t += 3) {
        GITER(0, t);
        GITER(1, t + 1);
        GITER(2, t + 2);
    }
    if (t < NT) { GITER(0, t); ++t; }
    if (t < NT) { GITER(1, t); }
#undef GITER
#undef GSTAGE

    const int r0 = (lane >> 4) * 4;
    const int cn = lane & 15;
#pragma unroll
    for (int mf = 0; mf < MF; ++mf) {
#pragma unroll
        for (int nf = 0; nf < NF; ++nf) {
            const int col = n0 + wn * (BN / WAVES_N) + nf * 16 + cn;
            const float bv = bias[col] * ((col < qcols) ? qs : 1.0f);
#pragma unroll
            for (int r = 0; r < 4; ++r) {
                const int row = m0 + wm * (BM / WAVES_M) + mf * 16 + r0 + r;
                const float v = acc[mf][nf][r] + bv;
                if constexpr (sizeof(OutT) == 2)
                    out[(size_t)row * N + col] = (OutT)f2bf(v);
                else
                    out[(size_t)row * N + col] = (OutT)v;
            }
        }
    }
}

// ---------------------------------------------------------------------------
// Flash attention v8.2 — v8.1 body (EXP2F softmax, KVBLK=64, qt[2], in-block
// causal pairing, K XOR-swizzle, permlane P redistribution, ones-V row-sum)
// with K in a 3-BUFFER rotation + counted-wait barriers (gemm3 T4 pattern):
// iter t stages K(t+2); end-of-iter barrier is lgkmcnt(0)+s_barrier only —
// NO vmcnt drain. Ledger: V(t+1) regs are issued BEFORE K(t+2) gll, so the
// V-pack's register wait (vmcnt(2)) retires K(t+1) — exactly what the next
// iter reads — while K(t+2) stays in flight across the barrier.
// ---------------------------------------------------------------------------
template <int BUF>
__device__ __forceinline__ void attn_iter(
    int KB, int niter, int qrow, int w, int cn, int g, int kg8,
    int krow, int kx0, int kx1, int skv, int sd0,
    const short* kgl, size_t ksrc, const short* vbase,
    short (*klds)[64 * 64], short (*vt)[64 * 72],
    const bf16x8 (&qf)[2][2], f32x4 (&ao)[2][4], f32x4 (&ao4)[2],
    const bf16x8& vones) {

    const int kvb = KB * 64;
    const bool pf = (KB + 1 < niter);
    const int vcur = KB & 1;

    // prefetch: V(t+1) to regs FIRST (older in vmcnt order), then K(t+2)
    // straight to LDS buf (BUF+2)%3 (newer; survives the barrier in flight)
    bf16x8 r0, r1;
    if (pf) {
        r0 = *(const bf16x8*)(vbase + (size_t)(kvb + 64 + skv) * C3 + sd0);
        r1 = *(const bf16x8*)(vbase + (size_t)(kvb + 64 + skv + 1) * C3 + sd0);
        const int kt2 = (KB + 2 < niter) ? (kvb + 128) : 0;   // wrap: uniform+safe
        const short* kn = kgl + ksrc + (size_t)kt2 * C3;
        __builtin_amdgcn_global_load_lds((const AS1 void*)kn,
            (AS3 void*)&klds[(BUF + 2) % 3][w * 512], 16, 0, 0);
        __builtin_amdgcn_global_load_lds((const AS1 void*)(kn + (size_t)32 * C3),
            (AS3 void*)&klds[(BUF + 2) % 3][2048 + w * 512], 16, 0, 0);
    }

    if (kvb <= qrow + 31) {   // wave-uniform: skip fully-masked iters
        bf16x8 kf[4][2];
#pragma unroll
        for (int t = 0; t < 4; ++t) {
            const int rb = t * 1024 + krow;
            kf[t][0] = *(const bf16x8*)&klds[BUF][rb + kx0];
            kf[t][1] = *(const bf16x8*)&klds[BUF][rb + kx1];
        }

        bf16x8 vf[2][4];
#pragma unroll
        for (int c = 0; c < 2; ++c)
#pragma unroll
            for (int dt = 0; dt < 4; ++dt)
                vf[c][dt] = *(const bf16x8*)&vt[vcur][(dt * 16 + cn) * 72 + c * 32 + kg8];

#pragma unroll
        for (int qt = 0; qt < 2; ++qt) {
            const int qrow16 = qrow + qt * 16;

            f32x4 s[4] = {};
#pragma unroll
            for (int t = 0; t < 4; ++t) {
                s[t] = mfma16(kf[t][0], qf[qt][0], s[t]);
                s[t] = mfma16(kf[t][1], qf[qt][1], s[t]);
            }

            const bool maskIter = (kvb + 63 > qrow16);
            float p[4][4];
            if (maskIter) {
#pragma unroll
                for (int t = 0; t < 4; ++t)
#pragma unroll
                    for (int r = 0; r < 4; ++r) {
                        const int kv = kvb + t * 16 + 4 * g + r;
                        const int q  = qrow16 + cn;
                        float e = EXP2F(s[t][r]);
                        p[t][r] = (kv > q) ? 0.f : e;
                    }
            } else {
#pragma unroll
                for (int t = 0; t < 4; ++t)
#pragma unroll
                    for (int r = 0; r < 4; ++r)
                        p[t][r] = EXP2F(s[t][r]);
            }

            unsigned int wq[8];
#pragma unroll
            for (int t = 0; t < 4; ++t) {
                wq[t * 2 + 0] = cvtpk(p[t][0], p[t][1]);
                wq[t * 2 + 1] = cvtpk(p[t][2], p[t][3]);
            }

#pragma unroll
            for (int c = 0; c < 2; ++c) {
                union { unsigned int u[4]; bf16x8 v; } pu;
                unsigned int p0 = wq[4 * c + 0], p2 = wq[4 * c + 2];
                asm("v_permlane32_swap_b32 %0, %1" : "+v"(p0), "+v"(p2));
                asm("v_permlane16_swap_b32 %0, %1" : "+v"(p0), "+v"(p2));
                pu.u[0] = p0; pu.u[2] = p2;
                unsigned int p1 = wq[4 * c + 1], p3 = wq[4 * c + 3];
                asm("v_permlane32_swap_b32 %0, %1" : "+v"(p1), "+v"(p3));
                asm("v_permlane16_swap_b32 %0, %1" : "+v"(p1), "+v"(p3));
                pu.u[1] = p1; pu.u[3] = p3;
#pragma unroll
                for (int dt = 0; dt < 4; ++dt)
                    ao[qt][dt] = mfma16(pu.v, vf[c][dt], ao[qt][dt]);
                ao4[qt] = mfma16(pu.v, vones, ao4[qt]);
            }
        }
    }

    // V pack-write (consumes r0/r1 -> compiler vmcnt wait retires K(t+1))
    if (pf) {
#pragma unroll
        for (int i = 0; i < 8; ++i) {
            unsigned int pk = (unsigned short)r0[i] | ((unsigned int)(unsigned short)r1[i] << 16);
            *(unsigned int*)&vt[vcur ^ 1][(sd0 + i) * 72 + skv] = pk;
        }
    }
    // counted barrier: drain LDS writes only; K(t+2) gll stays in flight
    asm volatile("s_waitcnt lgkmcnt(0)" ::: "memory");
    __builtin_amdgcn_s_barrier();
}

__global__ __launch_bounds__(256) void attn_kernel(const short* __restrict__ qkv,
                                                   short* __restrict__ attn_out) {
    __shared__ short vt[2][64 * 72];     // [buf][d*72 + kv]
    __shared__ short klds[3][64 * 64];   // 3-buf rotation, 16B-chunk XOR-swizzled

    const int tid = threadIdx.x;
    const int lane = tid & 63;
    const int w = tid >> 6;

    // XCD swizzle: 512 blocks, 64 per XCD; 8 bh per XCD
    const int bid = blockIdx.x;
    const int swz = (bid & 7) * 64 + (bid >> 3);
    const int bh = swz >> 3;             // 0..63
    const int pairp = swz & 7;           // 0..7
    const int b = bh >> 4;
    const int h = bh & 15;

    const size_t base = (size_t)b * TSEQ * C3 + (size_t)h * HDIM;
    const int cn = lane & 15;
    const int g = lane >> 4;
    const int kg8 = g * 8;

    const bf16x8 vones = {0x3F80, 0x3F80, 0x3F80, 0x3F80,
                          0x3F80, 0x3F80, 0x3F80, 0x3F80};

    const short* kgl = qkv + base + 1024;
    const size_t ksrc = (size_t)(w * 8 + (lane >> 3)) * C3 + ((lane & 7) ^ (lane >> 3)) * 8;
    const int cnl = cn & 7;
    const int krow = cn * 64;
    const int kx0 = ((g ^ cnl) * 8);
    const int kx1 = (((g ^ 4) ^ cnl) * 8);

    const int skv = (tid & 31) * 2;
    const int sd0 = (tid >> 5) * 8;
    const short* vbase = qkv + base + 2048;

    for (int pass = 0; pass < 2; ++pass) {
        const int qi = pass ? pairp : (15 - pairp);
        const int q0 = qi * 128;
        const int qrow = q0 + w * 32;
        const int niter = 2 * qi + 2;    // always >= 2, even

        bf16x8 qf[2][2];
#pragma unroll
        for (int qt = 0; qt < 2; ++qt)
#pragma unroll
            for (int ks = 0; ks < 2; ++ks)
                qf[qt][ks] = *(const bf16x8*)(qkv + base +
                    (size_t)(qrow + qt * 16 + cn) * C3 + ks * 32 + kg8);

        f32x4 ao[2][4] = {};
        f32x4 ao4[2] = {};

        {   // prologue: V0 regs (oldest), then K0 -> buf0, K1 -> buf1.
            // vmcnt(2) before barrier retires K0 (K1 stays in flight).
            bf16x8 r0 = *(const bf16x8*)(vbase + (size_t)skv * C3 + sd0);
            bf16x8 r1 = *(const bf16x8*)(vbase + (size_t)(skv + 1) * C3 + sd0);
            __builtin_amdgcn_global_load_lds((const AS1 void*)(kgl + ksrc),
                                             (AS3 void*)&klds[0][w * 512], 16, 0, 0);
            __builtin_amdgcn_global_load_lds((const AS1 void*)(kgl + ksrc + (size_t)32 * C3),
                                             (AS3 void*)&klds[0][2048 + w * 512], 16, 0, 0);
            __builtin_amdgcn_global_load_lds((const AS1 void*)(kgl + ksrc + (size_t)64 * C3),
                                             (AS3 void*)&klds[1][w * 512], 16, 0, 0);
            __builtin_amdgcn_global_load_lds((const AS1 void*)(kgl + ksrc + (size_t)96 * C3),
                                             (AS3 void*)&klds[1][2048 + w * 512], 16, 0, 0);
#pragma unroll
            for (int i = 0; i < 8; ++i) {
                unsigned int pk = (unsigned short)r0[i] | ((unsigned int)(unsigned short)r1[i] << 16);
                *(unsigned int*)&vt[0][(sd0 + i) * 72 + skv] = pk;
            }
            asm volatile("s_waitcnt vmcnt(2) lgkmcnt(0)" ::: "memory");
            __builtin_amdgcn_s_barrier();
        }

        int kb = 0;
        for (; kb + 3 <= niter; kb += 3) {
            attn_iter<0>(kb,     niter, qrow, w, cn, g, kg8, krow, kx0, kx1,
                         skv, sd0, kgl, ksrc, vbase, klds, vt, qf, ao, ao4, vones);
            attn_iter<1>(kb + 1, niter, qrow, w, cn, g, kg8, krow, kx0, kx1,
                         skv, sd0, kgl, ksrc, vbase, klds, vt, qf, ao, ao4, vones);
            attn_iter<2>(kb + 2, niter, qrow, w, cn, g, kg8, krow, kx0, kx1,
                         skv, sd0, kgl, ksrc, vbase, klds, vt, qf, ao, ao4, vones);
        }
        // tails: kb % 3 == 0 after the loop, so buffers are 0 then 1
        if (kb < niter) {
            attn_iter<0>(kb, niter, qrow, w, cn, g, kg8, krow, kx0, kx1,
                         skv, sd0, kgl, ksrc, vbase, klds, vt, qf, ao, ao4, vones);
            ++kb;
        }
        if (kb < niter) {
            attn_iter<1>(kb, niter, qrow, w, cn, g, kg8, krow, kx0, kx1,
                         skv, sd0, kgl, ksrc, vbase, klds, vt, qf, ao, ao4, vones);
        }

#pragma unroll
        for (int qt = 0; qt < 2; ++qt) {
#pragma unroll
            for (int r = 0; r < 4; ++r) {
                const float lr = 1.0f / ao4[qt][r];
                const int q = qrow + qt * 16 + 4 * g + r;
#pragma unroll
                for (int dt = 0; dt < 4; ++dt)
                    attn_out[(size_t)(b * TSEQ + q) * CDIM + h * HDIM + dt * 16 + cn] =
                        f2bf(ao[qt][dt][r] * lr);
            }
        }
        __syncthreads();   // full drain before next pass restages LDS
    }
}

// ---------------------------------------------------------------------------
// launch
// ---------------------------------------------------------------------------
extern "C" void kernel_launch(void* const* d_in, const int* in_sizes, int n_in,
                              void* d_out, int out_size, void* d_ws, size_t ws_size,
                              hipStream_t stream) {
    const float* x      = (const float*)d_in[0];
    const float* w_attn = (const float*)d_in[1];
    const float* b_attn = (const float*)d_in[2];
    const float* w_proj = (const float*)d_in[3];
    const float* b_proj = (const float*)d_in[4];
    float* out = (float*)d_out;

    char* ws = (char*)d_ws;
    short* x_bf   = (short*)ws;                          // 16 MiB; reused as attn out
    short* wqkvT  = (short*)(ws + (16u << 20));          //  6 MiB [3072][1024]
    short* wprojT = (short*)(ws + (22u << 20));          //  2 MiB [1024][1024]
    short* qkv    = (short*)(ws + (24u << 20));          // 48 MiB [8192][3072]

    prep_kernel<<<dim3(128, 32, 3), dim3(32, 8), 0, stream>>>(
        x, x_bf, w_attn, wqkvT, w_proj, wprojT, QSCALE);

    // GEMM1: M=8192, N=3072 -> gemm3<2,4,256> grid 12 x 64 = 768 blocks
    gemm3_kernel<short, 2, 4, 256><<<dim3(C3 / 256, MROWS / 128), 512, 0, stream>>>(
        x_bf, wqkvT, b_attn, qkv, MROWS, C3, CDIM, CDIM, QSCALE);

    attn_kernel<<<dim3(512), 256, 0, stream>>>(qkv, x_bf);

    // GEMM2: M=8192, N=1024 -> gemm3 grid 8 x 64 = 512 blocks = 2/CU balanced
    gemm3_kernel<float, 4, 2, 128><<<dim3(CDIM / 128, MROWS / 128), 512, 0, stream>>>(
        x_bf, wprojT, b_proj, out, MROWS, CDIM, CDIM, 0, 1.0f);
}

// Round 21
// 157.954 us; speedup vs baseline: 1.0192x; 1.0192x over previous
//
#include <hip/hip_runtime.h>
#include <hip/hip_bf16.h>

// ---------------------------------------------------------------------------
// Problem constants: B=4, T=2048, C=1024, H=16, hd=64
// ---------------------------------------------------------------------------
#define BATCH 4
#define TSEQ  2048
#define CDIM  1024
#define NHEAD 16
#define HDIM  64
#define C3    3072
#define MROWS (BATCH * TSEQ)   // 8192

// scale * log2(e): folded into w_attn q-columns + b_attn q-part so QK^T
// emits exp2-domain scores directly.
#define QSCALE 0.18033688011112f

typedef short bf16x8 __attribute__((ext_vector_type(8)));
typedef short short8 __attribute__((ext_vector_type(8)));
typedef __bf16 bf16v8 __attribute__((ext_vector_type(8)));
typedef float f32x4 __attribute__((ext_vector_type(4)));
typedef unsigned int u32x4v __attribute__((ext_vector_type(4)));

#define AS1 __attribute__((address_space(1)))
#define AS3 __attribute__((address_space(3)))

// raw v_exp_f32 (1 TRANS op) vs libm exp2f (denormal-guard ~5 ops). Inputs
// are bounded exp2-domain scores -> raw is exact for our range. (r15: -23%)
#if __has_builtin(__builtin_amdgcn_exp2f)
#define EXP2F(x) __builtin_amdgcn_exp2f(x)
#else
#define EXP2F(x) exp2f(x)
#endif

__device__ __forceinline__ short f2bf(float x) {
    unsigned int u = __builtin_bit_cast(unsigned int, x);
    u += 0x7fffu + ((u >> 16) & 1u);   // round-to-nearest-even
    return (short)(u >> 16);
}

__device__ __forceinline__ unsigned int cvtpk(float lo, float hi) {
    unsigned int r;
    asm("v_cvt_pk_bf16_f32 %0, %1, %2" : "=v"(r) : "v"(lo), "v"(hi));
    return r;
}

__device__ __forceinline__ f32x4 mfma16(bf16x8 a, bf16x8 b, f32x4 c) {
    return __builtin_amdgcn_mfma_f32_16x16x32_bf16(
        __builtin_bit_cast(bf16v8, a), __builtin_bit_cast(bf16v8, b), c, 0, 0, 0);
}

// pack V row-pair (r0,r1) into [d][kv] LDS words via v_perm_b32 (1 op/word
// vs ~3 for and+shl+or). Byte map verified: lo = [a.b0,a.b1,b.b0,b.b1] =
// (r0_low16)|(r1_low16<<16); hi likewise for the odd element.
__device__ __forceinline__ void vpack_write(short* dst, const bf16x8& r0,
                                            const bf16x8& r1, int skv, int sd0) {
#if __has_builtin(__builtin_amdgcn_perm)
    u32x4v a = __builtin_bit_cast(u32x4v, r0);
    u32x4v b = __builtin_bit_cast(u32x4v, r1);
#pragma unroll
    for (int wd = 0; wd < 4; ++wd) {
        unsigned int lo = __builtin_amdgcn_perm(b[wd], a[wd], 0x05040100u);
        unsigned int hi = __builtin_amdgcn_perm(b[wd], a[wd], 0x07060302u);
        *(unsigned int*)&dst[(sd0 + 2 * wd + 0) * 72 + skv] = lo;
        *(unsigned int*)&dst[(sd0 + 2 * wd + 1) * 72 + skv] = hi;
    }
#else
#pragma unroll
    for (int i = 0; i < 8; ++i) {
        unsigned int pk = (unsigned short)r0[i] | ((unsigned int)(unsigned short)r1[i] << 16);
        *(unsigned int*)&dst[(sd0 + i) * 72 + skv] = pk;
    }
#endif
}

// ---------------------------------------------------------------------------
// Merged prep: z=0 -> x fp32->bf16 convert; z=1 -> w_attn transpose (q-cols
// prescaled); z=2 -> w_proj transpose.
// ---------------------------------------------------------------------------
__global__ void prep_kernel(const float* __restrict__ x, short* __restrict__ x_bf,
                            const float* __restrict__ wA, short* __restrict__ wAT,
                            const float* __restrict__ wP, short* __restrict__ wPT,
                            float qs) {
    const int tx = threadIdx.x, ty = threadIdx.y;   // (32,8)
    if (blockIdx.z == 0) {
        const int i = (blockIdx.y * 128 + blockIdx.x) * 256 + ty * 32 + tx;
        float4 a = ((const float4*)x)[2 * i];
        float4 b = ((const float4*)x)[2 * i + 1];
        short8 o;
        o[0] = f2bf(a.x); o[1] = f2bf(a.y); o[2] = f2bf(a.z); o[3] = f2bf(a.w);
        o[4] = f2bf(b.x); o[5] = f2bf(b.y); o[6] = f2bf(b.z); o[7] = f2bf(b.w);
        ((short8*)x_bf)[i] = o;
        return;
    }
    const float* in;
    short* out;
    int N, qcols;
    float sc;
    if (blockIdx.z == 1) {
        if (blockIdx.x >= C3 / 32) return;
        in = wA; out = wAT; N = C3; qcols = CDIM; sc = qs;
    } else {
        if (blockIdx.x >= CDIM / 32) return;
        in = wP; out = wPT; N = CDIM; qcols = 0; sc = 1.0f;
    }
    __shared__ float tile[32][33];
    const int n0 = blockIdx.x * 32, k0 = blockIdx.y * 32;
#pragma unroll
    for (int j = 0; j < 4; ++j)
        tile[ty + j * 8][tx] = in[(size_t)(k0 + ty + j * 8) * N + n0 + tx];
    __syncthreads();
#pragma unroll
    for (int j = 0; j < 4; ++j) {
        const int n = n0 + ty + j * 8;
        const float s = (n < qcols) ? sc : 1.0f;
        out[(size_t)n * CDIM + k0 + tx] = f2bf(tile[tx][ty + j * 8] * s);
    }
}

// ---------------------------------------------------------------------------
// bf16 GEMM v3.1 (round-13/15 proven): BK=32 3-buffer rotation, counted-vmcnt
// pipeline, issue-early staging, chunk-XOR swizzle, bijective XCD swizzle.
// GEMM1 uses <2,4,256> (64x64 per-wave tile — verified sweet spot).
// ---------------------------------------------------------------------------
template <typename OutT, int WAVES_M, int WAVES_N, int BN>
__global__ __launch_bounds__(512, 4) void gemm3_kernel(
    const short* __restrict__ A, const short* __restrict__ Bt,
    const float* __restrict__ bias, OutT* __restrict__ out,
    int M, int N, int K, int qcols, float qs) {
    constexpr int BM = 128;
    constexpr int MF = BM / (WAVES_M * 16);
    constexpr int NF = BN / (WAVES_N * 16);
    constexpr int BLOADS = BN / 128;
    __shared__ alignas(16) short Ab[3][BM * 32];
    __shared__ alignas(16) short Bb[3][BN * 32];

    const int tid = threadIdx.x;
    const int lane = tid & 63;
    const int w = tid >> 6;
    const int wm = w / WAVES_N;
    const int wn = w % WAVES_N;

    const int nwg = gridDim.x * gridDim.y;
    const int lid = blockIdx.y * gridDim.x + blockIdx.x;
    const int swz = (lid & 7) * (nwg >> 3) + (lid >> 3);
    const int m0 = (swz / gridDim.x) * BM;
    const int n0 = (swz % gridDim.x) * BN;

    const int NT = K >> 5;

    const int fr = lane & 15;
    const int ch = lane >> 4;

    f32x4 acc[MF][NF] = {};

    const int rA  = tid >> 2;
    const int lcA = (tid & 3) ^ ((rA >> 1) & 3);
    const short* gA = A + (size_t)(m0 + rA) * K + lcA * 8;
    const short* gB[BLOADS];
#pragma unroll
    for (int i = 0; i < BLOADS; ++i) {
        const int s = tid + i * 512;
        const int r = s >> 2;
        const int lc = (s & 3) ^ ((r >> 1) & 3);
        gB[i] = Bt + (size_t)(n0 + r) * K + lc * 8;
    }

    int aoff[MF], boff[NF];
#pragma unroll
    for (int f = 0; f < MF; ++f) {
        const int r = wm * (BM / WAVES_M) + f * 16 + fr;
        aoff[f] = r * 32 + (ch ^ ((r >> 1) & 3)) * 8;
    }
#pragma unroll
    for (int f = 0; f < NF; ++f) {
        const int r = wn * (BN / WAVES_N) + f * 16 + fr;
        boff[f] = r * 32 + (ch ^ ((r >> 1) & 3)) * 8;
    }

#define GSTAGE(buf, kt)                                                          \
    do {                                                                         \
        __builtin_amdgcn_global_load_lds((const AS1 void*)(gA + (kt)),           \
            (AS3 void*)&Ab[buf][w * 512], 16, 0, 0);                             \
        _Pragma("unroll")                                                        \
        for (int i = 0; i < BLOADS; ++i)                                         \
            __builtin_amdgcn_global_load_lds((const AS1 void*)(gB[i] + (kt)),    \
                (AS3 void*)&Bb[buf][i * 4096 + w * 512], 16, 0, 0);              \
    } while (0)

#define GITER(BUF, T)                                                            \
    do {                                                                         \
        if constexpr (BLOADS == 2) {                                             \
            asm volatile("s_waitcnt vmcnt(3)" ::: "memory");                     \
        } else {                                                                 \
            asm volatile("s_waitcnt vmcnt(2)" ::: "memory");                     \
        }                                                                        \
        __builtin_amdgcn_s_barrier();                                            \
        const int ktn = (((T) + 2 < NT) ? ((T) + 2) : 0) * 32;                   \
        GSTAGE((BUF + 2) % 3, ktn);                                              \
        __builtin_amdgcn_sched_barrier(0);                                       \
        bf16x8 af[MF], bfv[NF];                                                  \
        _Pragma("unroll")                                                        \
        for (int f = 0; f < MF; ++f)                                             \
            af[f] = *(const bf16x8*)&Ab[BUF][aoff[f]];                           \
        _Pragma("unroll")                                                        \
        for (int f = 0; f < NF; ++f)                                             \
            bfv[f] = *(const bf16x8*)&Bb[BUF][boff[f]];                          \
        _Pragma("unroll")                                                        \
        for (int mf = 0; mf < MF; ++mf)                                          \
            _Pragma("unroll")                                                    \
            for (int nf = 0; nf < NF; ++nf)                                      \
                acc[mf][nf] = mfma16(af[mf], bfv[nf], acc[mf][nf]);              \
    } while (0)

    GSTAGE(0, 0);
    GSTAGE(1, 32);

    int t = 0;
    for (; t + 3 <= NT; t += 3) {
        GITER(0, t);
        GITER(1, t + 1);
        GITER(2, t + 2);
    }
    if (t < NT) { GITER(0, t); ++t; }
    if (t < NT) { GITER(1, t); }
#undef GITER
#undef GSTAGE

    const int r0 = (lane >> 4) * 4;
    const int cn = lane & 15;
#pragma unroll
    for (int mf = 0; mf < MF; ++mf) {
#pragma unroll
        for (int nf = 0; nf < NF; ++nf) {
            const int col = n0 + wn * (BN / WAVES_N) + nf * 16 + cn;
            const float bv = bias[col] * ((col < qcols) ? qs : 1.0f);
#pragma unroll
            for (int r = 0; r < 4; ++r) {
                const int row = m0 + wm * (BM / WAVES_M) + mf * 16 + r0 + r;
                const float v = acc[mf][nf][r] + bv;
                if constexpr (sizeof(OutT) == 2)
                    out[(size_t)row * N + col] = (OutT)f2bf(v);
                else
                    out[(size_t)row * N + col] = (OutT)v;
            }
        }
    }
}

// ---------------------------------------------------------------------------
// Flash attention v8.1 — round-19 structure (verified 67.7us; r20's counted-
// barrier K-3buf reverted: null-to-negative). EXP2F softmax, KVBLK=64, qt[2],
// in-block causal pairing (15-p, p): 512 uniform blocks = 2/CU; K XOR-swizzled
// LDS dbuf, V^T LDS dbuf (v_perm pack — this round's single variable),
// permlane P redistribution, ones-V row-sum MFMA.
// ---------------------------------------------------------------------------
template <int BUF>
__device__ __forceinline__ void attn_iter(
    int KB, int niter, int qrow, int w, int cn, int g, int kg8,
    int krow, int kx0, int kx1, int skv, int sd0,
    const short* kgl, size_t ksrc, const short* vbase,
    short (*klds)[64 * 64], short (*vt)[64 * 72],
    const bf16x8 (&qf)[2][2], f32x4 (&ao)[2][4], f32x4 (&ao4)[2],
    const bf16x8& vones) {

    const int kvb = KB * 64;
    const bool pf = (KB + 1 < niter);

    // prefetch next tile: V to regs first, then K straight to LDS
    bf16x8 r0, r1;
    if (pf) {
        r0 = *(const bf16x8*)(vbase + (size_t)(kvb + 64 + skv) * C3 + sd0);
        r1 = *(const bf16x8*)(vbase + (size_t)(kvb + 64 + skv + 1) * C3 + sd0);
        const short* kn = kgl + ksrc + (size_t)(kvb + 64) * C3;
        __builtin_amdgcn_global_load_lds((const AS1 void*)kn,
            (AS3 void*)&klds[BUF ^ 1][w * 512], 16, 0, 0);
        __builtin_amdgcn_global_load_lds((const AS1 void*)(kn + (size_t)32 * C3),
            (AS3 void*)&klds[BUF ^ 1][2048 + w * 512], 16, 0, 0);
    }

    if (kvb <= qrow + 31) {   // wave-uniform: skip fully-masked iters
        bf16x8 kf[4][2];
#pragma unroll
        for (int t = 0; t < 4; ++t) {
            const int rb = t * 1024 + krow;
            kf[t][0] = *(const bf16x8*)&klds[BUF][rb + kx0];
            kf[t][1] = *(const bf16x8*)&klds[BUF][rb + kx1];
        }

        bf16x8 vf[2][4];
#pragma unroll
        for (int c = 0; c < 2; ++c)
#pragma unroll
            for (int dt = 0; dt < 4; ++dt)
                vf[c][dt] = *(const bf16x8*)&vt[BUF][(dt * 16 + cn) * 72 + c * 32 + kg8];

#pragma unroll
        for (int qt = 0; qt < 2; ++qt) {
            const int qrow16 = qrow + qt * 16;

            f32x4 s[4] = {};
#pragma unroll
            for (int t = 0; t < 4; ++t) {
                s[t] = mfma16(kf[t][0], qf[qt][0], s[t]);
                s[t] = mfma16(kf[t][1], qf[qt][1], s[t]);
            }

            const bool maskIter = (kvb + 63 > qrow16);
            float p[4][4];
            if (maskIter) {
#pragma unroll
                for (int t = 0; t < 4; ++t)
#pragma unroll
                    for (int r = 0; r < 4; ++r) {
                        const int kv = kvb + t * 16 + 4 * g + r;
                        const int q  = qrow16 + cn;
                        float e = EXP2F(s[t][r]);
                        p[t][r] = (kv > q) ? 0.f : e;
                    }
            } else {
#pragma unroll
                for (int t = 0; t < 4; ++t)
#pragma unroll
                    for (int r = 0; r < 4; ++r)
                        p[t][r] = EXP2F(s[t][r]);
            }

            unsigned int wq[8];
#pragma unroll
            for (int t = 0; t < 4; ++t) {
                wq[t * 2 + 0] = cvtpk(p[t][0], p[t][1]);
                wq[t * 2 + 1] = cvtpk(p[t][2], p[t][3]);
            }

#pragma unroll
            for (int c = 0; c < 2; ++c) {
                union { unsigned int u[4]; bf16x8 v; } pu;
                unsigned int p0 = wq[4 * c + 0], p2 = wq[4 * c + 2];
                asm("v_permlane32_swap_b32 %0, %1" : "+v"(p0), "+v"(p2));
                asm("v_permlane16_swap_b32 %0, %1" : "+v"(p0), "+v"(p2));
                pu.u[0] = p0; pu.u[2] = p2;
                unsigned int p1 = wq[4 * c + 1], p3 = wq[4 * c + 3];
                asm("v_permlane32_swap_b32 %0, %1" : "+v"(p1), "+v"(p3));
                asm("v_permlane16_swap_b32 %0, %1" : "+v"(p1), "+v"(p3));
                pu.u[1] = p1; pu.u[3] = p3;
#pragma unroll
                for (int dt = 0; dt < 4; ++dt)
                    ao[qt][dt] = mfma16(pu.v, vf[c][dt], ao[qt][dt]);
                ao4[qt] = mfma16(pu.v, vones, ao4[qt]);
            }
        }
    }

    if (pf) vpack_write(vt[BUF ^ 1], r0, r1, skv, sd0);
    __syncthreads();
}

__global__ __launch_bounds__(256) void attn_kernel(const short* __restrict__ qkv,
                                                   short* __restrict__ attn_out) {
    __shared__ short vt[2][64 * 72];     // [buf][d*72 + kv]
    __shared__ short klds[2][64 * 64];   // [buf][kv*64 + d], 16B-chunk XOR-swizzled

    const int tid = threadIdx.x;
    const int lane = tid & 63;
    const int w = tid >> 6;

    // XCD swizzle: 512 blocks, 64 per XCD; 8 bh per XCD
    const int bid = blockIdx.x;
    const int swz = (bid & 7) * 64 + (bid >> 3);
    const int bh = swz >> 3;             // 0..63
    const int pairp = swz & 7;           // 0..7
    const int b = bh >> 4;
    const int h = bh & 15;

    const size_t base = (size_t)b * TSEQ * C3 + (size_t)h * HDIM;
    const int cn = lane & 15;
    const int g = lane >> 4;
    const int kg8 = g * 8;

    const bf16x8 vones = {0x3F80, 0x3F80, 0x3F80, 0x3F80,
                          0x3F80, 0x3F80, 0x3F80, 0x3F80};

    const short* kgl = qkv + base + 1024;
    const size_t ksrc = (size_t)(w * 8 + (lane >> 3)) * C3 + ((lane & 7) ^ (lane >> 3)) * 8;
    const int cnl = cn & 7;
    const int krow = cn * 64;
    const int kx0 = ((g ^ cnl) * 8);
    const int kx1 = (((g ^ 4) ^ cnl) * 8);

    const int skv = (tid & 31) * 2;
    const int sd0 = (tid >> 5) * 8;
    const short* vbase = qkv + base + 2048;

    for (int pass = 0; pass < 2; ++pass) {
        const int qi = pass ? pairp : (15 - pairp);
        const int q0 = qi * 128;
        const int qrow = q0 + w * 32;
        const int niter = 2 * qi + 2;

        bf16x8 qf[2][2];
#pragma unroll
        for (int qt = 0; qt < 2; ++qt)
#pragma unroll
            for (int ks = 0; ks < 2; ++ks)
                qf[qt][ks] = *(const bf16x8*)(qkv + base +
                    (size_t)(qrow + qt * 16 + cn) * C3 + ks * 32 + kg8);

        f32x4 ao[2][4] = {};
        f32x4 ao4[2] = {};

        {   // prologue: stage K0 + V0
            __builtin_amdgcn_global_load_lds((const AS1 void*)(kgl + ksrc),
                                             (AS3 void*)&klds[0][w * 512], 16, 0, 0);
            __builtin_amdgcn_global_load_lds((const AS1 void*)(kgl + ksrc + (size_t)32 * C3),
                                             (AS3 void*)&klds[0][2048 + w * 512], 16, 0, 0);
            bf16x8 r0 = *(const bf16x8*)(vbase + (size_t)skv * C3 + sd0);
            bf16x8 r1 = *(const bf16x8*)(vbase + (size_t)(skv + 1) * C3 + sd0);
            vpack_write(vt[0], r0, r1, skv, sd0);
        }
        __syncthreads();

        int kb = 0;
        for (; kb + 2 <= niter; kb += 2) {
            attn_iter<0>(kb,     niter, qrow, w, cn, g, kg8, krow, kx0, kx1,
                         skv, sd0, kgl, ksrc, vbase, klds, vt, qf, ao, ao4, vones);
            attn_iter<1>(kb + 1, niter, qrow, w, cn, g, kg8, krow, kx0, kx1,
                         skv, sd0, kgl, ksrc, vbase, klds, vt, qf, ao, ao4, vones);
        }

#pragma unroll
        for (int qt = 0; qt < 2; ++qt) {
#pragma unroll
            for (int r = 0; r < 4; ++r) {
                const float lr = 1.0f / ao4[qt][r];
                const int q = qrow + qt * 16 + 4 * g + r;
#pragma unroll
                for (int dt = 0; dt < 4; ++dt)
                    attn_out[(size_t)(b * TSEQ + q) * CDIM + h * HDIM + dt * 16 + cn] =
                        f2bf(ao[qt][dt][r] * lr);
            }
        }
        __syncthreads();   // protect LDS before next pass restages
    }
}

// ---------------------------------------------------------------------------
// launch
// ---------------------------------------------------------------------------
extern "C" void kernel_launch(void* const* d_in, const int* in_sizes, int n_in,
                              void* d_out, int out_size, void* d_ws, size_t ws_size,
                              hipStream_t stream) {
    const float* x      = (const float*)d_in[0];
    const float* w_attn = (const float*)d_in[1];
    const float* b_attn = (const float*)d_in[2];
    const float* w_proj = (const float*)d_in[3];
    const float* b_proj = (const float*)d_in[4];
    float* out = (float*)d_out;

    char* ws = (char*)d_ws;
    short* x_bf   = (short*)ws;                          // 16 MiB; reused as attn out
    short* wqkvT  = (short*)(ws + (16u << 20));          //  6 MiB [3072][1024]
    short* wprojT = (short*)(ws + (22u << 20));          //  2 MiB [1024][1024]
    short* qkv    = (short*)(ws + (24u << 20));          // 48 MiB [8192][3072]

    prep_kernel<<<dim3(128, 32, 3), dim3(32, 8), 0, stream>>>(
        x, x_bf, w_attn, wqkvT, w_proj, wprojT, QSCALE);

    // GEMM1: M=8192, N=3072 -> gemm3<2,4,256> grid 12 x 64 = 768 blocks
    gemm3_kernel<short, 2, 4, 256><<<dim3(C3 / 256, MROWS / 128), 512, 0, stream>>>(
        x_bf, wqkvT, b_attn, qkv, MROWS, C3, CDIM, CDIM, QSCALE);

    attn_kernel<<<dim3(512), 256, 0, stream>>>(qkv, x_bf);

    // GEMM2: M=8192, N=1024 -> gemm3 grid 8 x 64 = 512 blocks = 2/CU balanced
    gemm3_kernel<float, 4, 2, 128><<<dim3(CDIM / 128, MROWS / 128), 512, 0, stream>>>(
        x_bf, wprojT, b_proj, out, MROWS, CDIM, CDIM, 0, 1.0f);
}